// Round 1
// baseline (260.707 us; speedup 1.0000x reference)
//
#include <hip/hip_runtime.h>

#define IMG_H 512
#define IMG_W 512
#define TW 32
#define TH 32
#define HALO 5
#define IW (TW + 2 * HALO)   // 42
#define IH (TH + 2 * HALO)   // 42
#define SPS 45               // padded LDS row stride (odd -> spreads banks)

// 1D Gaussian (sigma=1.5, K=11), computed in float64 and rounded to fp32.
__device__ __constant__ float WIN[11] = {
    0.00102838f, 0.00759876f, 0.03600077f, 0.10936069f, 0.21300554f,
    0.26601173f,
    0.21300554f, 0.10936069f, 0.03600077f, 0.00759876f, 0.00102838f
};

__global__ __launch_bounds__(256) void ssim_tile_kernel(
        const float* __restrict__ pred, const float* __restrict__ gt,
        double* __restrict__ accum)
{
    __shared__ float sp[IH * SPS];
    __shared__ float sg[IH * SPS];
    __shared__ float hp [IH * TW];
    __shared__ float hg [IH * TW];
    __shared__ float hpp[IH * TW];
    __shared__ float hgg[IH * TW];
    __shared__ float hpg[IH * TW];
    __shared__ float wsum[4];

    const int tid = threadIdx.x;
    const int plane = blockIdx.z;
    const long base = (long)plane * (IMG_H * IMG_W);
    const int y0 = blockIdx.y * TH - HALO;
    const int x0 = blockIdx.x * TW - HALO;

    // ---- stage input tile (+halo), zero padding outside the image ----
    for (int e = tid; e < IH * IW; e += 256) {
        int r = e / IW, c = e - r * IW;
        int gr = y0 + r, gc = x0 + c;
        float pv = 0.f, gv = 0.f;
        if ((unsigned)gr < IMG_H && (unsigned)gc < IMG_W) {
            long idx = base + (long)gr * IMG_W + gc;
            pv = pred[idx];
            gv = gt[idx];
        }
        sp[r * SPS + c] = pv;
        sg[r * SPS + c] = gv;
    }
    __syncthreads();

    // ---- horizontal separable pass: IH rows x TW cols of 5 intermediates.
    // Each unit produces 4 consecutive outputs via a register sliding window.
    for (int u = tid; u < IH * (TW / 4); u += 256) {
        int r  = u >> 3;          // row 0..41
        int c0 = (u & 7) * 4;     // col group 0,4,...,28
        float a1[4] = {0,0,0,0}, a2[4] = {0,0,0,0}, a3[4] = {0,0,0,0};
        float a4[4] = {0,0,0,0}, a5[4] = {0,0,0,0};
        const float* prow = &sp[r * SPS + c0];
        const float* grow = &sg[r * SPS + c0];
#pragma unroll
        for (int m = 0; m < 14; ++m) {
            float pv = prow[m], gv = grow[m];
            float ppv = pv * pv, ggv = gv * gv, pgv = pv * gv;
#pragma unroll
            for (int j = 0; j < 4; ++j) {
                int k = m - j;
                if (k >= 0 && k < 11) {
                    float wk = WIN[k];
                    a1[j] = fmaf(wk, pv,  a1[j]);
                    a2[j] = fmaf(wk, gv,  a2[j]);
                    a3[j] = fmaf(wk, ppv, a3[j]);
                    a4[j] = fmaf(wk, ggv, a4[j]);
                    a5[j] = fmaf(wk, pgv, a5[j]);
                }
            }
        }
#pragma unroll
        for (int j = 0; j < 4; ++j) {
            hp [r * TW + c0 + j] = a1[j];
            hg [r * TW + c0 + j] = a2[j];
            hpp[r * TW + c0 + j] = a3[j];
            hgg[r * TW + c0 + j] = a4[j];
            hpg[r * TW + c0 + j] = a5[j];
        }
    }
    __syncthreads();

    // ---- vertical pass + SSIM map: each thread does a 4-row column strip ----
    const int c  = tid & 31;
    const int r0 = (tid >> 5) * 4;
    float m1[4]  = {0,0,0,0}, m2[4]  = {0,0,0,0};
    float s11[4] = {0,0,0,0}, s22[4] = {0,0,0,0}, s12[4] = {0,0,0,0};
#pragma unroll
    for (int m = 0; m < 14; ++m) {
        int row = r0 + m;
        float vp  = hp [row * TW + c];
        float vg  = hg [row * TW + c];
        float vpp = hpp[row * TW + c];
        float vgg = hgg[row * TW + c];
        float vpg = hpg[row * TW + c];
#pragma unroll
        for (int j = 0; j < 4; ++j) {
            int k = m - j;
            if (k >= 0 && k < 11) {
                float wk = WIN[k];
                m1[j]  = fmaf(wk, vp,  m1[j]);
                m2[j]  = fmaf(wk, vg,  m2[j]);
                s11[j] = fmaf(wk, vpp, s11[j]);
                s22[j] = fmaf(wk, vgg, s22[j]);
                s12[j] = fmaf(wk, vpg, s12[j]);
            }
        }
    }

    const float C1 = 1e-4f, C2 = 9e-4f;
    float lsum = 0.f;
#pragma unroll
    for (int j = 0; j < 4; ++j) {
        float mu1 = m1[j], mu2 = m2[j];
        float mu1sq = mu1 * mu1, mu2sq = mu2 * mu2, mu12 = mu1 * mu2;
        float sig1  = s11[j] - mu1sq;
        float sig2  = s22[j] - mu2sq;
        float sig12 = s12[j] - mu12;
        float num = (2.f * mu12 + C1) * (2.f * sig12 + C2);
        float den = (mu1sq + mu2sq + C1) * (sig1 + sig2 + C2);
        lsum += num / den;
    }

    // ---- block reduction: wave shfl -> LDS -> one double atomic ----
#pragma unroll
    for (int off = 32; off > 0; off >>= 1)
        lsum += __shfl_down(lsum, off);
    if ((tid & 63) == 0) wsum[tid >> 6] = lsum;
    __syncthreads();
    if (tid == 0) {
        float s = wsum[0] + wsum[1] + wsum[2] + wsum[3];
        atomicAdd(accum, (double)s);
    }
}

__global__ void ssim_finalize(const double* __restrict__ accum,
                              float* __restrict__ out, double inv_n)
{
    out[0] = 1.0f - (float)(accum[0] * inv_n);
}

extern "C" void kernel_launch(void* const* d_in, const int* in_sizes, int n_in,
                              void* d_out, int out_size, void* d_ws, size_t ws_size,
                              hipStream_t stream)
{
    const float* pred = (const float*)d_in[0];
    const float* gt   = (const float*)d_in[1];
    float* out        = (float*)d_out;
    double* accum     = (double*)d_ws;

    const long n = (long)in_sizes[0];
    const int planes = (int)(n / (long)(IMG_H * IMG_W));   // B*C = 48

    hipMemsetAsync(accum, 0, sizeof(double), stream);
    dim3 grid(IMG_W / TW, IMG_H / TH, planes);
    ssim_tile_kernel<<<grid, 256, 0, stream>>>(pred, gt, accum);
    ssim_finalize<<<1, 1, 0, stream>>>(accum, out, 1.0 / (double)n);
}

// Round 2
// 197.776 us; speedup vs baseline: 1.3182x; 1.3182x over previous
//
#include <hip/hip_runtime.h>

#define IMG_H 512
#define IMG_W 512
#define TW 32
#define TH 32
#define HALO 5
#define IH (TH + 2 * HALO)     // 42 intermediate rows
#define LS 36                  // LDS row stride: (4r+c)%32 spreads banks, keeps 16B align
#define NUNITS (IH * (TW / 4)) // 336 horizontal units per tile

typedef float v4 __attribute__((ext_vector_type(4)));

// 1D Gaussian (sigma=1.5, K=11) — same values that passed round 1 with absmax 0.
#define G0 0.00102838f
#define G1 0.00759876f
#define G2 0.03600077f
#define G3 0.10936069f
#define G4 0.21300554f
#define G5 0.26601173f

// W4c[m][j] = w[m-j] (0 outside [0,10]): tap table for 4-wide sliding window,
// shared by H and V passes. Zero-padded -> no guards, pure v_pk_fma_f32.
__device__ __constant__ float W4c[14][4] = {
    {G0, 0,  0,  0 }, {G1, G0, 0,  0 }, {G2, G1, G0, 0 }, {G3, G2, G1, G0},
    {G4, G3, G2, G1}, {G5, G4, G3, G2}, {G4, G5, G4, G3}, {G3, G4, G5, G4},
    {G2, G3, G4, G5}, {G1, G2, G3, G4}, {G0, G1, G2, G3}, {0,  G0, G1, G2},
    {0,  0,  G0, G1}, {0,  0,  0,  G0}};

__global__ __launch_bounds__(256, 5) void ssim_tile_kernel(
        const float* __restrict__ pred, const float* __restrict__ gt,
        float* __restrict__ partials)
{
    // 5 intermediate arrays (H-pass results), stride-36 padded, 30.2 KB total.
    __shared__ __attribute__((aligned(16))) float hp [IH * LS];
    __shared__ __attribute__((aligned(16))) float hg [IH * LS];
    __shared__ __attribute__((aligned(16))) float hpp[IH * LS];
    __shared__ __attribute__((aligned(16))) float hgg[IH * LS];
    __shared__ __attribute__((aligned(16))) float hpg[IH * LS];
    __shared__ float wsum[4];

    const int tid = threadIdx.x;
    const int bx = blockIdx.x, by = blockIdx.y, plane = blockIdx.z;
    const long base = (long)plane * (IMG_H * IMG_W);
    // interior blocks: every window read [gr][cbase..cbase+19] is in-bounds
    const bool interior = (bx >= 1 && bx <= 14 && by >= 1 && by <= 14);

    // ---- horizontal pass: unit u makes 4 consecutive H-outputs of 5 channels
    for (int u = tid; u < NUNITS; u += 256) {
        const int r  = u >> 3;
        const int c0 = (u & 7) << 2;
        const int gr = by * TH - HALO + r;
        const int cbase = bx * TW + c0 - 8;     // 16B-aligned window start
        float pw[20], gw[20];

        if (interior) {
            const float4* p4 = (const float4*)(pred + base + (long)gr * IMG_W + cbase);
            const float4* g4 = (const float4*)(gt   + base + (long)gr * IMG_W + cbase);
#pragma unroll
            for (int i = 0; i < 5; ++i) {
                *(float4*)&pw[4 * i] = p4[i];
                *(float4*)&gw[4 * i] = g4[i];
            }
        } else {
            const bool rowok = (unsigned)gr < IMG_H;
            const long rowoff = base + (long)gr * IMG_W;
#pragma unroll
            for (int i = 0; i < 20; ++i) {
                const int cc = cbase + i;
                const bool ok = rowok && ((unsigned)cc < IMG_W);
                pw[i] = ok ? pred[rowoff + cc] : 0.f;
                gw[i] = ok ? gt  [rowoff + cc] : 0.f;
            }
        }

        v4 a1 = 0, a2 = 0, a3 = 0, a4 = 0, a5 = 0;
#pragma unroll
        for (int m = 0; m < 14; ++m) {
            const float pv = pw[m + 3], gv = gw[m + 3];
            const v4 w  = *(const v4*)W4c[m];
            const v4 ps = {pv, pv, pv, pv};
            const v4 gs = {gv, gv, gv, gv};
            const float ppv = pv * pv, ggv = gv * gv, pgv = pv * gv;
            const v4 pps = {ppv, ppv, ppv, ppv};
            const v4 ggs = {ggv, ggv, ggv, ggv};
            const v4 pgs = {pgv, pgv, pgv, pgv};
            a1 = __builtin_elementwise_fma(w, ps,  a1);
            a2 = __builtin_elementwise_fma(w, gs,  a2);
            a3 = __builtin_elementwise_fma(w, pps, a3);
            a4 = __builtin_elementwise_fma(w, ggs, a4);
            a5 = __builtin_elementwise_fma(w, pgs, a5);
        }
        const int o = r * LS + c0;              // multiple of 4 -> 16B aligned
        *(v4*)&hp [o] = a1;
        *(v4*)&hg [o] = a2;
        *(v4*)&hpp[o] = a3;
        *(v4*)&hgg[o] = a4;
        *(v4*)&hpg[o] = a5;
    }
    __syncthreads();

    // ---- vertical pass + SSIM map: thread = (col, 4-row strip) ----
    const int c   = tid & 31;
    const int r0g = (tid >> 5) << 2;
    v4 m1 = 0, m2 = 0, s11 = 0, s22 = 0, s12 = 0;
#pragma unroll
    for (int m = 0; m < 14; ++m) {
        const int o = (r0g + m) * LS + c;
        const float vp  = hp [o];
        const float vg  = hg [o];
        const float vpp = hpp[o];
        const float vgg = hgg[o];
        const float vpg = hpg[o];
        const v4 w = *(const v4*)W4c[m];
        const v4 a = {vp, vp, vp, vp};
        const v4 b = {vg, vg, vg, vg};
        const v4 d = {vpp, vpp, vpp, vpp};
        const v4 e = {vgg, vgg, vgg, vgg};
        const v4 f = {vpg, vpg, vpg, vpg};
        m1  = __builtin_elementwise_fma(w, a, m1);
        m2  = __builtin_elementwise_fma(w, b, m2);
        s11 = __builtin_elementwise_fma(w, d, s11);
        s22 = __builtin_elementwise_fma(w, e, s22);
        s12 = __builtin_elementwise_fma(w, f, s12);
    }

    const float C1 = 1e-4f, C2 = 9e-4f;
    float lsum = 0.f;
#pragma unroll
    for (int j = 0; j < 4; ++j) {
        const float mu1 = m1[j], mu2 = m2[j];
        const float mu1sq = mu1 * mu1, mu2sq = mu2 * mu2, mu12 = mu1 * mu2;
        const float sig1  = s11[j] - mu1sq;
        const float sig2  = s22[j] - mu2sq;
        const float sig12 = s12[j] - mu12;
        const float num = (2.f * mu12 + C1) * (2.f * sig12 + C2);
        const float den = (mu1sq + mu2sq + C1) * (sig1 + sig2 + C2);
        lsum += num * __builtin_amdgcn_rcpf(den);
    }

    // ---- block reduction -> one partial per block (no init needed) ----
#pragma unroll
    for (int off = 32; off > 0; off >>= 1)
        lsum += __shfl_down(lsum, off);
    if ((tid & 63) == 0) wsum[tid >> 6] = lsum;
    __syncthreads();
    if (tid == 0)
        partials[((plane * 16) + by) * 16 + bx] =
            wsum[0] + wsum[1] + wsum[2] + wsum[3];
}

__global__ __launch_bounds__(1024) void ssim_finalize(
        const float* __restrict__ partials, float* __restrict__ out,
        int nparts, double inv_n)
{
    __shared__ double ws[16];
    double s = 0.0;
    for (int i = threadIdx.x; i < nparts; i += 1024)
        s += (double)partials[i];
#pragma unroll
    for (int off = 32; off > 0; off >>= 1)
        s += __shfl_down(s, off);
    if ((threadIdx.x & 63) == 0) ws[threadIdx.x >> 6] = s;
    __syncthreads();
    if (threadIdx.x == 0) {
        double t = 0.0;
#pragma unroll
        for (int i = 0; i < 16; ++i) t += ws[i];
        out[0] = (float)(1.0 - t * inv_n);
    }
}

extern "C" void kernel_launch(void* const* d_in, const int* in_sizes, int n_in,
                              void* d_out, int out_size, void* d_ws, size_t ws_size,
                              hipStream_t stream)
{
    const float* pred = (const float*)d_in[0];
    const float* gt   = (const float*)d_in[1];
    float* out        = (float*)d_out;
    float* partials   = (float*)d_ws;          // 12288 floats = 48 KiB scratch

    const long n = (long)in_sizes[0];
    const int planes = (int)(n / (long)(IMG_H * IMG_W));   // B*C = 48

    dim3 grid(IMG_W / TW, IMG_H / TH, planes);
    ssim_tile_kernel<<<grid, 256, 0, stream>>>(pred, gt, partials);
    ssim_finalize<<<1, 1024, 0, stream>>>(partials, out,
                                          16 * 16 * planes, 1.0 / (double)n);
}

// Round 3
// 196.737 us; speedup vs baseline: 1.3252x; 1.0053x over previous
//
#include <hip/hip_runtime.h>

#define IMG_H 512
#define IMG_W 512
#define TW 32
#define TH 32
#define HALO 5
#define IH (TH + 2 * HALO)     // 42 intermediate rows
#define LS 36                  // LDS row stride: spreads banks, keeps 16B align
#define NUNITS (IH * (TW / 4)) // 336 horizontal units per tile

typedef float v4 __attribute__((ext_vector_type(4)));

// 1D Gaussian (sigma=1.5, K=11)
#define G0 0.00102838f
#define G1 0.00759876f
#define G2 0.03600077f
#define G3 0.10936069f
#define G4 0.21300554f
#define G5 0.26601173f

// W4c[m][j] = w[m-j] (0 outside [0,10]): tap table for 4-wide sliding window.
__device__ __constant__ float W4c[14][4] = {
    {G0, 0,  0,  0 }, {G1, G0, 0,  0 }, {G2, G1, G0, 0 }, {G3, G2, G1, G0},
    {G4, G3, G2, G1}, {G5, G4, G3, G2}, {G4, G5, G4, G3}, {G3, G4, G5, G4},
    {G2, G3, G4, G5}, {G1, G2, G3, G4}, {G0, G1, G2, G3}, {0,  G0, G1, G2},
    {0,  0,  G0, G1}, {0,  0,  0,  G0}};

__device__ __forceinline__ void load_windows(
        const float* __restrict__ pred, const float* __restrict__ gt,
        long base, int gr, int cbase, bool interior,
        float* __restrict__ pw, float* __restrict__ gw)
{
    if (interior) {
        const float4* p4 = (const float4*)(pred + base + (long)gr * IMG_W + cbase);
        const float4* g4 = (const float4*)(gt   + base + (long)gr * IMG_W + cbase);
#pragma unroll
        for (int i = 0; i < 5; ++i) {
            *(float4*)&pw[4 * i] = p4[i];
            *(float4*)&gw[4 * i] = g4[i];
        }
    } else {
        const bool rowok = (unsigned)gr < IMG_H;
        const long rowoff = base + (long)gr * IMG_W;
#pragma unroll
        for (int i = 0; i < 20; ++i) {
            const int cc = cbase + i;
            const bool ok = rowok && ((unsigned)cc < IMG_W);
            pw[i] = ok ? pred[rowoff + cc] : 0.f;
            gw[i] = ok ? gt  [rowoff + cc] : 0.f;
        }
    }
}

__device__ __forceinline__ void hconv_store(
        const float* __restrict__ pw, const float* __restrict__ gw, int o,
        float* __restrict__ hp, float* __restrict__ hg, float* __restrict__ hpp,
        float* __restrict__ hgg, float* __restrict__ hpg)
{
    v4 a1 = 0, a2 = 0, a3 = 0, a4 = 0, a5 = 0;
#pragma unroll
    for (int m = 0; m < 14; ++m) {
        const float pv = pw[m + 3], gv = gw[m + 3];
        const v4 w  = *(const v4*)W4c[m];
        const v4 ps = {pv, pv, pv, pv};
        const v4 gs = {gv, gv, gv, gv};
        const float ppv = pv * pv, ggv = gv * gv, pgv = pv * gv;
        const v4 pps = {ppv, ppv, ppv, ppv};
        const v4 ggs = {ggv, ggv, ggv, ggv};
        const v4 pgs = {pgv, pgv, pgv, pgv};
        a1 = __builtin_elementwise_fma(w, ps,  a1);
        a2 = __builtin_elementwise_fma(w, gs,  a2);
        a3 = __builtin_elementwise_fma(w, pps, a3);
        a4 = __builtin_elementwise_fma(w, ggs, a4);
        a5 = __builtin_elementwise_fma(w, pgs, a5);
    }
    *(v4*)&hp [o] = a1;
    *(v4*)&hg [o] = a2;
    *(v4*)&hpp[o] = a3;
    *(v4*)&hgg[o] = a4;
    *(v4*)&hpg[o] = a5;
}

__global__ __launch_bounds__(256, 4) void ssim_tile_kernel(
        const float* __restrict__ pred, const float* __restrict__ gt,
        float* __restrict__ partials)
{
    __shared__ __attribute__((aligned(16))) float hp [IH * LS];
    __shared__ __attribute__((aligned(16))) float hg [IH * LS];
    __shared__ __attribute__((aligned(16))) float hpp[IH * LS];
    __shared__ __attribute__((aligned(16))) float hgg[IH * LS];
    __shared__ __attribute__((aligned(16))) float hpg[IH * LS];
    __shared__ float wsum[4];

    const int tid = threadIdx.x;
    const int bx = blockIdx.x, by = blockIdx.y, plane = blockIdx.z;
    const long base = (long)plane * (IMG_H * IMG_W);
    const bool interior = (bx >= 1 && bx <= 14 && by >= 1 && by <= 14);

    // ---- horizontal pass: unit u = 4 consecutive H-outputs of all 5 channels.
    // 336 units: thread t owns unit t, and (t<80) unit t+256. ALL global loads
    // are issued before any FMA so unit B's latency hides under unit A's math.
    {
        const int uA = tid;
        const int rA = uA >> 3, cA = (uA & 7) << 2;
        const int grA = by * TH - HALO + rA;
        const int cbA = bx * TW + cA - 8;
        float pwA[20], gwA[20];
        load_windows(pred, gt, base, grA, cbA, interior, pwA, gwA);

        const bool hasB = tid < (NUNITS - 256);
        float pwB[20], gwB[20];
        int oB = 0;
        if (hasB) {
            const int uB = tid + 256;
            const int rB = uB >> 3, cB = (uB & 7) << 2;
            const int grB = by * TH - HALO + rB;
            const int cbB = bx * TW + cB - 8;
            oB = rB * LS + cB;
            load_windows(pred, gt, base, grB, cbB, interior, pwB, gwB);
        }

        hconv_store(pwA, gwA, rA * LS + cA, hp, hg, hpp, hgg, hpg);
        if (hasB)
            hconv_store(pwB, gwB, oB, hp, hg, hpp, hgg, hpg);
    }
    __syncthreads();

    // ---- vertical pass + SSIM map: thread = (col, 4-row strip).
    // Per channel: batch all 14 independent ds_reads, then 14 packed fma.
    const int c   = tid & 31;
    const int r0g = (tid >> 5) << 2;
    const int vb  = r0g * LS + c;
    v4 m1, m2, s11, s22, s12;

#define VCONV(arr, acc)                                                   \
    {                                                                     \
        float row[14];                                                    \
        _Pragma("unroll")                                                 \
        for (int m = 0; m < 14; ++m) row[m] = arr[vb + m * LS];           \
        acc = 0;                                                          \
        _Pragma("unroll")                                                 \
        for (int m = 0; m < 14; ++m) {                                    \
            const v4 w = *(const v4*)W4c[m];                              \
            const v4 x = {row[m], row[m], row[m], row[m]};                \
            acc = __builtin_elementwise_fma(w, x, acc);                   \
        }                                                                 \
    }
    VCONV(hp,  m1)
    VCONV(hg,  m2)
    VCONV(hpp, s11)
    VCONV(hgg, s22)
    VCONV(hpg, s12)
#undef VCONV

    const float C1 = 1e-4f, C2 = 9e-4f;
    float lsum = 0.f;
#pragma unroll
    for (int j = 0; j < 4; ++j) {
        const float mu1 = m1[j], mu2 = m2[j];
        const float mu1sq = mu1 * mu1, mu2sq = mu2 * mu2, mu12 = mu1 * mu2;
        const float sig1  = s11[j] - mu1sq;
        const float sig2  = s22[j] - mu2sq;
        const float sig12 = s12[j] - mu12;
        const float num = (2.f * mu12 + C1) * (2.f * sig12 + C2);
        const float den = (mu1sq + mu2sq + C1) * (sig1 + sig2 + C2);
        lsum += num * __builtin_amdgcn_rcpf(den);
    }

    // ---- block reduction -> one partial per block ----
#pragma unroll
    for (int off = 32; off > 0; off >>= 1)
        lsum += __shfl_down(lsum, off);
    if ((tid & 63) == 0) wsum[tid >> 6] = lsum;
    __syncthreads();
    if (tid == 0)
        partials[((plane * 16) + by) * 16 + bx] =
            wsum[0] + wsum[1] + wsum[2] + wsum[3];
}

__global__ __launch_bounds__(1024) void ssim_finalize(
        const float* __restrict__ partials, float* __restrict__ out,
        int nparts, double inv_n)
{
    __shared__ double ws[16];
    double s = 0.0;
    for (int i = threadIdx.x; i < nparts; i += 1024)
        s += (double)partials[i];
#pragma unroll
    for (int off = 32; off > 0; off >>= 1)
        s += __shfl_down(s, off);
    if ((threadIdx.x & 63) == 0) ws[threadIdx.x >> 6] = s;
    __syncthreads();
    if (threadIdx.x == 0) {
        double t = 0.0;
#pragma unroll
        for (int i = 0; i < 16; ++i) t += ws[i];
        out[0] = (float)(1.0 - t * inv_n);
    }
}

extern "C" void kernel_launch(void* const* d_in, const int* in_sizes, int n_in,
                              void* d_out, int out_size, void* d_ws, size_t ws_size,
                              hipStream_t stream)
{
    const float* pred = (const float*)d_in[0];
    const float* gt   = (const float*)d_in[1];
    float* out        = (float*)d_out;
    float* partials   = (float*)d_ws;

    const long n = (long)in_sizes[0];
    const int planes = (int)(n / (long)(IMG_H * IMG_W));   // B*C = 48

    dim3 grid(IMG_W / TW, IMG_H / TH, planes);
    ssim_tile_kernel<<<grid, 256, 0, stream>>>(pred, gt, partials);
    ssim_finalize<<<1, 1024, 0, stream>>>(partials, out,
                                          16 * 16 * planes, 1.0 / (double)n);
}

// Round 4
// 192.143 us; speedup vs baseline: 1.3568x; 1.0239x over previous
//
#include <hip/hip_runtime.h>

#define IMG 512
#define YCHUNK 32
#define NCHUNK 4            // 4*11 = 44 slots >= YCHUNK+10 active
typedef float v2f __attribute__((ext_vector_type(2)));
typedef float v4u __attribute__((ext_vector_type(4), aligned(4)));  // unaligned-safe

// 1D Gaussian (sigma=1.5, K=11) — identical values to rounds 1-3 (absmax 0.0).
__device__ static constexpr float W11[11] = {
    0.00102838f, 0.00759876f, 0.03600077f, 0.10936069f, 0.21300554f,
    0.26601173f,
    0.21300554f, 0.10936069f, 0.03600077f, 0.00759876f, 0.00102838f};

// One thread = one image column x, YCHUNK output rows, V-conv via an
// 11-slot register ring (static indices from the unroll-11 inner loop).
// No __shared__ tiles, no per-tile barriers.
__global__ __launch_bounds__(256, 4) void ssim_ring_kernel(
        const float* __restrict__ pred, const float* __restrict__ gt,
        float* __restrict__ partials)
{
    __shared__ float wsum[4];

    const int tid = threadIdx.x;
    const int w = tid >> 6, l = tid & 63;
    const int bx = blockIdx.x, by = blockIdx.y, plane = blockIdx.z;
    const long base = (long)plane * (IMG * IMG);
    const int x = bx * 256 + w * 64 + l;       // this thread's column
    const int y0 = by * YCHUNK;
    // waves whose 12-float windows can leave the image in x:
    const bool edge = (bx == 0 && w == 0) || (bx == 1 && w == 3);

    // ring: H-conv results for the last 11 input rows
    v2f  ring_ab[11];   // (conv p, conv g)
    v2f  ring_cd[11];   // (conv pp, conv gg)
    float ring_e[11];   // conv pg
    float lsum = 0.f;

    for (int c = 0; c < NCHUNK; ++c) {
#pragma unroll
        for (int u = 0; u < 11; ++u) {
            const int s = c * 11 + u;
            const int r = y0 - 5 + s;           // input row for this slot

            if (s < YCHUNK + 10) {
                // ---- load 12-float windows [x-5 .. x+6] of pred & gt ----
                float pw[12], gw[12];
                if ((unsigned)r < IMG) {
                    const float* pr = pred + base + (long)r * IMG;
                    const float* gr = gt   + base + (long)r * IMG;
                    if (!edge) {
                        *(v4u*)&pw[0] = *(const v4u*)(pr + x - 5);
                        *(v4u*)&pw[4] = *(const v4u*)(pr + x - 1);
                        *(v4u*)&pw[8] = *(const v4u*)(pr + x + 3);
                        *(v4u*)&gw[0] = *(const v4u*)(gr + x - 5);
                        *(v4u*)&gw[4] = *(const v4u*)(gr + x - 1);
                        *(v4u*)&gw[8] = *(const v4u*)(gr + x + 3);
                    } else {
#pragma unroll
                        for (int t = 0; t < 12; ++t) {
                            const int cc = x - 5 + t;
                            const bool ok = (unsigned)cc < IMG;
                            const int cs = ok ? cc : 0;
                            pw[t] = ok ? pr[cs] : 0.f;
                            gw[t] = ok ? gr[cs] : 0.f;
                        }
                    }
                } else {
#pragma unroll
                    for (int t = 0; t < 12; ++t) { pw[t] = 0.f; gw[t] = 0.f; }
                }

                // ---- H-conv (scalar; avoids VOP3P pairing movs) ----
                float a = 0.f, b = 0.f, cc2 = 0.f, d = 0.f, e = 0.f;
#pragma unroll
                for (int t = 0; t < 11; ++t) {
                    const float wt = W11[t];
                    const float pv = pw[t], gv = gw[t];
                    a = fmaf(wt, pv, a);
                    b = fmaf(wt, gv, b);
                    cc2 = fmaf(wt, pv * pv, cc2);
                    d = fmaf(wt, gv * gv, d);
                    e = fmaf(wt, pv * gv, e);
                }
                ring_ab[u] = (v2f){a, b};
                ring_cd[u] = (v2f){cc2, d};
                ring_e[u]  = e;
            }

            // ---- emit output y = y0 + s - 10 ----
            if (s >= 10 && s < YCHUNK + 10) {
                v2f mu = (v2f)0.f, S = (v2f)0.f;
                float s12 = 0.f;
#pragma unroll
                for (int q = 0; q < 11; ++q) {
                    // tap index t = (q - u + 10) mod 11
                    const float wt = W11[(q - u + 21) % 11];
                    const v2f ws = {wt, wt};
                    mu = __builtin_elementwise_fma(ws, ring_ab[q], mu);
                    S  = __builtin_elementwise_fma(ws, ring_cd[q], S);
                    s12 = fmaf(wt, ring_e[q], s12);
                }
                const float C1 = 1e-4f, C2 = 9e-4f;
                const float mu1 = mu.x, mu2 = mu.y;
                const float mu1sq = mu1 * mu1, mu2sq = mu2 * mu2;
                const float mu12 = mu1 * mu2;
                const float sig1 = S.x - mu1sq, sig2 = S.y - mu2sq;
                const float sg12 = s12 - mu12;
                const float num = (2.f * mu12 + C1) * (2.f * sg12 + C2);
                const float den = (mu1sq + mu2sq + C1) * (sig1 + sig2 + C2);
                lsum += num * __builtin_amdgcn_rcpf(den);
            }
        }
    }

    // ---- block reduction -> one partial per block ----
#pragma unroll
    for (int off = 32; off > 0; off >>= 1)
        lsum += __shfl_down(lsum, off);
    if ((tid & 63) == 0) wsum[tid >> 6] = lsum;
    __syncthreads();
    if (tid == 0)
        partials[bx + 2 * (by + 16 * plane)] =
            wsum[0] + wsum[1] + wsum[2] + wsum[3];
}

__global__ __launch_bounds__(1024) void ssim_finalize(
        const float* __restrict__ partials, float* __restrict__ out,
        int nparts, double inv_n)
{
    __shared__ double ws[16];
    double s = 0.0;
    for (int i = threadIdx.x; i < nparts; i += 1024)
        s += (double)partials[i];
#pragma unroll
    for (int off = 32; off > 0; off >>= 1)
        s += __shfl_down(s, off);
    if ((threadIdx.x & 63) == 0) ws[threadIdx.x >> 6] = s;
    __syncthreads();
    if (threadIdx.x == 0) {
        double t = 0.0;
#pragma unroll
        for (int i = 0; i < 16; ++i) t += ws[i];
        out[0] = (float)(1.0 - t * inv_n);
    }
}

extern "C" void kernel_launch(void* const* d_in, const int* in_sizes, int n_in,
                              void* d_out, int out_size, void* d_ws, size_t ws_size,
                              hipStream_t stream)
{
    const float* pred = (const float*)d_in[0];
    const float* gt   = (const float*)d_in[1];
    float* out        = (float*)d_out;
    float* partials   = (float*)d_ws;          // 1536 floats

    const long n = (long)in_sizes[0];
    const int planes = (int)(n / (long)(IMG * IMG));   // B*C = 48

    dim3 grid(2, IMG / YCHUNK, planes);                // 2 x 16 x 48 = 1536
    ssim_ring_kernel<<<grid, 256, 0, stream>>>(pred, gt, partials);
    ssim_finalize<<<1, 1024, 0, stream>>>(partials, out,
                                          2 * 16 * planes, 1.0 / (double)n);
}

// Round 5
// 180.438 us; speedup vs baseline: 1.4449x; 1.0649x over previous
//
#include <hip/hip_runtime.h>

#define IMG 512

typedef short short8  __attribute__((ext_vector_type(8)));
typedef float floatx4 __attribute__((ext_vector_type(4)));
typedef int   intx2   __attribute__((ext_vector_type(2)));

// 1D Gaussian (sigma=1.5, K=11) — identical values to rounds 1-4 (absmax 0.0).
__device__ static constexpr float W11F[11] = {
    0.00102838f, 0.00759876f, 0.03600077f, 0.10936069f, 0.21300554f,
    0.26601173f,
    0.21300554f, 0.10936069f, 0.03600077f, 0.00759876f, 0.00102838f};

// pack two fp32 -> two bf16 bits (round-half-up; values are finite, positive)
__device__ __forceinline__ unsigned pack2bf16(float a, float b) {
    const unsigned ua = __float_as_uint(a) + 0x8000u;
    const unsigned ub = __float_as_uint(b) + 0x8000u;
    return __builtin_amdgcn_perm(ub, ua, 0x07060302u);  // {hi16(a), hi16(b)}
}

#define HT_CS 36                 // shorts per Ht column (32 data + 4 pad = 72 B)
#define HT_CH (64 * HT_CS)       // shorts per channel

__device__ __forceinline__ void ht_store(ushort* p, floatx4 c) {
    intx2 d;
    d.x = (int)pack2bf16(c[0], c[1]);
    d.y = (int)pack2bf16(c[2], c[3]);
    *(intx2*)p = d;              // 8-B aligned by construction
}

__device__ __forceinline__ short8 ht_load(const ushort* p) {
    union { intx2 d[2]; short8 s; } u;
    u.d[0] = *(const intx2*)p;
    u.d[1] = *(const intx2*)(p + 4);
    return u.s;
}

__global__ __launch_bounds__(256, 4) void ssim_mfma_kernel(
        const float* __restrict__ pred, const float* __restrict__ gt,
        float* __restrict__ partials)
{
    __shared__ ushort Ht[5 * HT_CH];   // [ch][col 0..63][k 0..31], 23 KB
    __shared__ ushort wlut[16];
    __shared__ float wsum[4];

    const int tid  = threadIdx.x;
    const int wv   = tid >> 6;         // wave 0..3
    const int lane = tid & 63;
    const int n    = lane & 15;        // MFMA 15-index (A row / B col / C col)
    const int quad = lane >> 4;        // MFMA quad

    // ---- bf16 weight LUT; wlut[11..15] = 0 for out-of-band taps ----
    if (tid < 16) {
        const float w = (tid < 11) ? W11F[tid] : 0.f;
        wlut[tid] = (ushort)((__float_as_uint(w) + 0x8000u) >> 16);
    }
    __syncthreads();

    // ---- band fragment: value w[(quad*8+j) - n - 3].
    // Serves as B in H-pass (B[i][n]=w[i-n-3]) AND A in V-pass (A[m][k]=w[k-m-3]).
    short8 band;
#pragma unroll
    for (int j = 0; j < 8; ++j) {
        const int t = quad * 8 + j - n - 3;
        band[j] = (short)wlut[((unsigned)t < 11u) ? t : 15];
    }

    const int bx = blockIdx.x, by = blockIdx.y, plane = blockIdx.z;
    const long pb = (long)plane * (IMG * IMG);
    const int x0  = bx * 64;
    const int y0  = by * 16;
    const int xs  = x0 + wv * 16 - 8;  // this wave's 32-col K-window start
    const int xpo = wv * 16;           // this wave's col offset in Ht

    // ================= H pass: 2 row-tiles x 5 channels ==================
#pragma unroll
    for (int rt = 0; rt < 2; ++rt) {
        const int ys  = y0 - 8 + rt * 16;
        const int row = ys + n;
        const int c0  = xs + quad * 8;
        float pf[8], gf[8];

        const bool rows_ok = (ys >= 0) && (ys + 16 <= IMG);
        const bool cols_ok = (xs >= 0) && (xs + 32 <= IMG);
        if (rows_ok && cols_ok) {
            const float* pr = pred + pb + (long)row * IMG + c0;
            const float* gr = gt   + pb + (long)row * IMG + c0;
            *(float4*)&pf[0] = *(const float4*)pr;
            *(float4*)&pf[4] = *(const float4*)(pr + 4);
            *(float4*)&gf[0] = *(const float4*)gr;
            *(float4*)&gf[4] = *(const float4*)(gr + 4);
        } else {
            const bool rv = (unsigned)row < (unsigned)IMG;
            const int rowc = rv ? row : 0;
            const float* pr = pred + pb + (long)rowc * IMG;
            const float* gr = gt   + pb + (long)rowc * IMG;
#pragma unroll
            for (int j = 0; j < 8; ++j) {
                const int cc = c0 + j;
                const bool ok = rv && ((unsigned)cc < (unsigned)IMG);
                const int ccc = ok ? cc : 0;
                const float pv = pr[ccc], gv = gr[ccc];
                pf[j] = ok ? pv : 0.f;
                gf[j] = ok ? gv : 0.f;
            }
        }

        // fp32 -> bf16 A-fragments for the 5 channels
        union { unsigned u[4]; short8 s; } ap, ag, app, agg, apg;
#pragma unroll
        for (int h = 0; h < 4; ++h) {
            const float p0 = pf[2*h], p1 = pf[2*h+1];
            const float g0 = gf[2*h], g1 = gf[2*h+1];
            ap.u [h] = pack2bf16(p0, p1);
            ag.u [h] = pack2bf16(g0, g1);
            app.u[h] = pack2bf16(p0 * p0, p1 * p1);
            agg.u[h] = pack2bf16(g0 * g0, g1 * g1);
            apg.u[h] = pack2bf16(p0 * g0, p1 * g1);
        }

        const floatx4 z = {0.f, 0.f, 0.f, 0.f};
        const floatx4 cp  = __builtin_amdgcn_mfma_f32_16x16x32_bf16(ap.s,  band, z, 0, 0, 0);
        const floatx4 cg  = __builtin_amdgcn_mfma_f32_16x16x32_bf16(ag.s,  band, z, 0, 0, 0);
        const floatx4 cpp = __builtin_amdgcn_mfma_f32_16x16x32_bf16(app.s, band, z, 0, 0, 0);
        const floatx4 cgg = __builtin_amdgcn_mfma_f32_16x16x32_bf16(agg.s, band, z, 0, 0, 0);
        const floatx4 cpg = __builtin_amdgcn_mfma_f32_16x16x32_bf16(apg.s, band, z, 0, 0, 0);

        // C layout: n = lane&15 (out-col), m = quad*4+reg (data row) -> Ht[col][k]
        const int wb = (xpo + n) * HT_CS + rt * 16 + quad * 4;
        ht_store(&Ht[0 * HT_CH + wb], cp);
        ht_store(&Ht[1 * HT_CH + wb], cg);
        ht_store(&Ht[2 * HT_CH + wb], cpp);
        ht_store(&Ht[3 * HT_CH + wb], cgg);
        ht_store(&Ht[4 * HT_CH + wb], cpg);
    }
    // no barrier needed: each wave reads back only its own Ht columns,
    // and within-wave LDS RAW is ordered by the DS pipe.

    // ================= V pass: band x Ht, 5 channels ==================
    const int rb = (xpo + n) * HT_CS + quad * 8;
    const short8 bp  = ht_load(&Ht[0 * HT_CH + rb]);
    const short8 bg  = ht_load(&Ht[1 * HT_CH + rb]);
    const short8 bpp = ht_load(&Ht[2 * HT_CH + rb]);
    const short8 bgg = ht_load(&Ht[3 * HT_CH + rb]);
    const short8 bpg = ht_load(&Ht[4 * HT_CH + rb]);

    const floatx4 z = {0.f, 0.f, 0.f, 0.f};
    const floatx4 mp  = __builtin_amdgcn_mfma_f32_16x16x32_bf16(band, bp,  z, 0, 0, 0);
    const floatx4 mg  = __builtin_amdgcn_mfma_f32_16x16x32_bf16(band, bg,  z, 0, 0, 0);
    const floatx4 mpp = __builtin_amdgcn_mfma_f32_16x16x32_bf16(band, bpp, z, 0, 0, 0);
    const floatx4 mgg = __builtin_amdgcn_mfma_f32_16x16x32_bf16(band, bgg, z, 0, 0, 0);
    const floatx4 mpg = __builtin_amdgcn_mfma_f32_16x16x32_bf16(band, bpg, z, 0, 0, 0);

    // ---- SSIM map from C-layout registers (channels share (row,col)/lane) ----
    const float C1 = 1e-4f, C2 = 9e-4f;
    float lsum = 0.f;
#pragma unroll
    for (int r = 0; r < 4; ++r) {
        const float mu1 = mp[r], mu2 = mg[r];
        const float mu1sq = mu1 * mu1, mu2sq = mu2 * mu2, mu12 = mu1 * mu2;
        const float s1  = mpp[r] - mu1sq;
        const float s2  = mgg[r] - mu2sq;
        const float s12 = mpg[r] - mu12;
        const float num = (2.f * mu12 + C1) * (2.f * s12 + C2);
        const float den = (mu1sq + mu2sq + C1) * (s1 + s2 + C2);
        lsum += num * __builtin_amdgcn_rcpf(den);
    }

    // ---- block reduction -> one partial per block ----
#pragma unroll
    for (int off = 32; off > 0; off >>= 1)
        lsum += __shfl_down(lsum, off);
    if ((tid & 63) == 0) wsum[tid >> 6] = lsum;
    __syncthreads();
    if (tid == 0)
        partials[(plane * 32 + by) * 8 + bx] =
            wsum[0] + wsum[1] + wsum[2] + wsum[3];
}

__global__ __launch_bounds__(1024) void ssim_finalize(
        const float* __restrict__ partials, float* __restrict__ out,
        int nparts, double inv_n)
{
    __shared__ double ws[16];
    double s = 0.0;
    for (int i = threadIdx.x; i < nparts; i += 1024)
        s += (double)partials[i];
#pragma unroll
    for (int off = 32; off > 0; off >>= 1)
        s += __shfl_down(s, off);
    if ((threadIdx.x & 63) == 0) ws[threadIdx.x >> 6] = s;
    __syncthreads();
    if (threadIdx.x == 0) {
        double t = 0.0;
#pragma unroll
        for (int i = 0; i < 16; ++i) t += ws[i];
        out[0] = (float)(1.0 - t * inv_n);
    }
}

extern "C" void kernel_launch(void* const* d_in, const int* in_sizes, int n_in,
                              void* d_out, int out_size, void* d_ws, size_t ws_size,
                              hipStream_t stream)
{
    const float* pred = (const float*)d_in[0];
    const float* gt   = (const float*)d_in[1];
    float* out        = (float*)d_out;
    float* partials   = (float*)d_ws;          // 8*32*48 = 12288 floats

    const long n = (long)in_sizes[0];
    const int planes = (int)(n / (long)(IMG * IMG));   // B*C = 48

    dim3 grid(8, 32, planes);                  // 64-col x 16-row tiles
    ssim_mfma_kernel<<<grid, 256, 0, stream>>>(pred, gt, partials);
    ssim_finalize<<<1, 1024, 0, stream>>>(partials, out,
                                          8 * 32 * planes, 1.0 / (double)n);
}